// Round 3
// baseline (193.941 us; speedup 1.0000x reference)
//
#include <hip/hip_runtime.h>
#include <cmath>

// Problem constants (fixed by the reference).
constexpr int B  = 4096;
constexpr int D  = 768;
constexpr int P  = 96;
constexpr int C  = 256;
constexpr int SD = 8;    // D / P

constexpr int TPB  = 64; // one wave per block
constexpr int ROWS = 4;  // batch rows per thread (amortizes LDS centroid reads)

// ---- numpy fp32 emulation helpers (exact path only) ------------------------
__device__ __forceinline__ float tree8(float q0, float q1, float q2, float q3,
                                       float q4, float q5, float q6, float q7)
{
#pragma clang fp contract(off)
    return ((q0 + q1) + (q2 + q3)) + ((q4 + q5) + (q6 + q7));
}

// proba[b,p,c] = -((v_sq - 2*vc) + c_sq), all fp32 roundings in numpy's order.
// vc: SSE2 npyv sum-of-products: p_i=fl(v_i*c_i); l_j=fl(p_j+p_{j+4});
//     vc=fl(fl(l0+l2)+fl(l1+l3))
__device__ __forceinline__ float proba_np(const float* __restrict__ cbf,
                                          const float* __restrict__ csq,
                                          int c, float4 va, float4 vb, float vsq)
{
#pragma clang fp contract(off)
    float4 ca = ((const float4*)cbf)[2 * c];
    float4 cb = ((const float4*)cbf)[2 * c + 1];
    float p0 = va.x * ca.x, p1 = va.y * ca.y, p2 = va.z * ca.z, p3 = va.w * ca.w;
    float p4 = vb.x * cb.x, p5 = vb.y * cb.y, p6 = vb.z * cb.z, p7 = vb.w * cb.w;
    float l0 = p0 + p4, l1 = p1 + p5, l2 = p2 + p6, l3 = p3 + p7;
    float vc = (l0 + l2) + (l1 + l3);
    float tt = vsq - 2.0f * vc;
    float u  = tt + csq[c];
    return -u;
}

// Exact numpy-order argmax for one (b,p) search, incl. the softmax tie path.
// Identical semantics to the round-1 kernel that measured absmax == 0.0.
__device__ __attribute__((noinline))
int exact_search(const float* __restrict__ cbf, const float* __restrict__ csq,
                 float4 va, float4 vb, float vsq)
{
#pragma clang fp contract(off)
    float best = -3.402823466e38f, second = -3.402823466e38f;
    int bi = 0;
    for (int c = 0; c < C; ++c) {
        float pr = proba_np(cbf, csq, c, va, vb, vsq);
        if (pr > best)        { second = best; best = pr; bi = c; }
        else if (pr > second) { second = pr; }
    }
    int idx = bi;

    if (best - second <= 1.0e-6f) {
        float m = best;
        // numpy pairwise sum over 256 = pair(128)+pair(128); each 128 uses 8
        // strided accumulators combined with tree8.
        float r0[8] = {0,0,0,0,0,0,0,0};
        float r1[8] = {0,0,0,0,0,0,0,0};
        for (int cg = 0; cg < 16; ++cg) {
            #pragma unroll
            for (int j = 0; j < 8; ++j) {
                float pr = proba_np(cbf, csq, cg * 8 + j, va, vb, vsq);
                r0[j] += expf(pr - m);
            }
        }
        for (int cg = 16; cg < 32; ++cg) {
            #pragma unroll
            for (int j = 0; j < 8; ++j) {
                float pr = proba_np(cbf, csq, cg * 8 + j, va, vb, vsq);
                r1[j] += expf(pr - m);
            }
        }
        float sum = tree8(r0[0],r0[1],r0[2],r0[3],r0[4],r0[5],r0[6],r0[7])
                  + tree8(r1[0],r1[1],r1[2],r1[3],r1[4],r1[5],r1[6],r1[7]);
        float abest = -1.0f;
        int   ai    = 0;
        for (int c = 0; c < C; ++c) {
            float pr = proba_np(cbf, csq, c, va, vb, vsq);
            float e  = expf(pr - m);
            float a  = e / sum;
            if (a > abest) { abest = a; ai = c; }
        }
        idx = ai;
    }
    return idx;
}

// One wave per block; thread t owns rows {base + t + 64*r}, all in partition p.
// Fast pass: s = dot8_fma(v,c) - 0.5*csq  (argmax-equivalent to proba).
// |fast-order - numpy-order| <= ~4.4e-6 in s units; rows whose top-2 fast gap
// is <= DELTA=2e-5 are re-run through the exact numpy emulation.
__global__ __launch_bounds__(TPB, 8)
void pq_fast_kernel(const float* __restrict__ vecs,
                    const float* __restrict__ codebook,
                    float* __restrict__ out)
{
    __shared__ float cbf [C * SD];  // 8 KB codebook[p]
    __shared__ float csqn[C];       // ||c||^2, numpy fp32 order (exact path)
    __shared__ float csqh[C];       // -0.5 * csqn (fast-path seed)

    const int p = blockIdx.x;
    const int t = threadIdx.x;
    const int base = blockIdx.y * (TPB * ROWS);

    // ---- stage codebook[p]: 512 float4, 8 per thread ----
    const float4* src = (const float4*)(codebook + (size_t)p * C * SD);
    #pragma unroll
    for (int i = 0; i < 8; ++i)
        ((float4*)cbf)[t + 64 * i] = src[t + 64 * i];
    __syncthreads();

    // ---- csq (numpy order) + fast seed, 4 centroids per thread ----
    #pragma unroll
    for (int k = 0; k < 4; ++k) {
        int c = t + 64 * k;
        const float* cc = cbf + c * SD;
        float q0 = cc[0]*cc[0], q1 = cc[1]*cc[1], q2 = cc[2]*cc[2], q3 = cc[3]*cc[3];
        float q4 = cc[4]*cc[4], q5 = cc[5]*cc[5], q6 = cc[6]*cc[6], q7 = cc[7]*cc[7];
        float s = tree8(q0,q1,q2,q3,q4,q5,q6,q7);
        csqn[c] = s;
        csqh[c] = -0.5f * s;
    }
    __syncthreads();

    // ---- load ROWS sub-vectors (issue all loads up front for MLP) ----
    float4 va[ROWS], vb[ROWS];
    #pragma unroll
    for (int r = 0; r < ROWS; ++r) {
        const float* vptr = vecs + (size_t)(base + 64 * r + t) * D + (size_t)p * SD;
        va[r] = ((const float4*)vptr)[0];
        vb[r] = ((const float4*)vptr)[1];
    }

    // vsq in numpy order (only the exact path needs it; cheap to precompute)
    float vsq[ROWS];
    #pragma unroll
    for (int r = 0; r < ROWS; ++r) {
        float q0 = va[r].x*va[r].x, q1 = va[r].y*va[r].y,
              q2 = va[r].z*va[r].z, q3 = va[r].w*va[r].w;
        float q4 = vb[r].x*vb[r].x, q5 = vb[r].y*vb[r].y,
              q6 = vb[r].z*vb[r].z, q7 = vb[r].w*vb[r].w;
        vsq[r] = tree8(q0,q1,q2,q3,q4,q5,q6,q7);
    }

    // ---- fast scoring loop: top-2 + index per row ----
    float best[ROWS], second[ROWS];
    int   bi[ROWS];
    #pragma unroll
    for (int r = 0; r < ROWS; ++r) {
        best[r] = -3.402823466e38f; second[r] = -3.402823466e38f; bi[r] = 0;
    }

    #pragma unroll 2
    for (int c = 0; c < C; ++c) {
        float4 ca = ((const float4*)cbf)[2 * c];      // broadcast ds_read_b128
        float4 cb = ((const float4*)cbf)[2 * c + 1];
        float  ch = csqh[c];                           // broadcast ds_read_b32
        #pragma unroll
        for (int r = 0; r < ROWS; ++r) {
            float s = fmaf(va[r].x, ca.x, ch);
            s = fmaf(va[r].y, ca.y, s);
            s = fmaf(va[r].z, ca.z, s);
            s = fmaf(va[r].w, ca.w, s);
            s = fmaf(vb[r].x, cb.x, s);
            s = fmaf(vb[r].y, cb.y, s);
            s = fmaf(vb[r].z, cb.z, s);
            s = fmaf(vb[r].w, cb.w, s);
            bool gt = s > best[r];
            second[r] = fmaxf(second[r], fminf(s, best[r]));
            bi[r]     = gt ? c : bi[r];
            best[r]   = fmaxf(s, best[r]);
        }
    }

    // ---- resolve + store ----
    #pragma unroll
    for (int r = 0; r < ROWS; ++r) {
        int idx = bi[r];
        if (best[r] - second[r] <= 2.0e-5f)     // near-tie: exact numpy path
            idx = exact_search(cbf, csqn, va[r], vb[r], vsq[r]);
        float4 o0 = ((const float4*)cbf)[2 * idx];
        float4 o1 = ((const float4*)cbf)[2 * idx + 1];
        float4* op = (float4*)(out + (size_t)(base + 64 * r + t) * D + (size_t)p * SD);
        op[0] = o0;
        op[1] = o1;
    }
}

extern "C" void kernel_launch(void* const* d_in, const int* in_sizes, int n_in,
                              void* d_out, int out_size, void* d_ws, size_t ws_size,
                              hipStream_t stream)
{
    const float* vecs     = (const float*)d_in[0];  // [B, D] fp32
    const float* codebook = (const float*)d_in[1];  // [P, C, SD] fp32
    float*       out      = (float*)d_out;          // [B, D] fp32

    dim3 grid(P, B / (TPB * ROWS));  // (96, 16) -> 1536 one-wave blocks
    dim3 block(TPB);
    pq_fast_kernel<<<grid, block, 0, stream>>>(vecs, codebook, out);
}

// Round 4
// 173.039 us; speedup vs baseline: 1.1208x; 1.1208x over previous
//
#include <hip/hip_runtime.h>
#include <cmath>

// Problem constants (fixed by the reference).
constexpr int B  = 4096;
constexpr int D  = 768;
constexpr int P  = 96;
constexpr int C  = 256;
constexpr int SD = 8;    // D / P

constexpr int TPB  = 256;   // 4 waves per block
constexpr int WPB  = 4;     // waves per block (centroid split)
constexpr int CPW  = C / WPB;  // 64 centroids per wave
constexpr int ROWS = 4;     // rows per thread (amortizes LDS centroid reads)

// ---- numpy fp32 emulation helpers (exact path only, validated absmax=0) ----
__device__ __forceinline__ float tree8(float q0, float q1, float q2, float q3,
                                       float q4, float q5, float q6, float q7)
{
#pragma clang fp contract(off)
    return ((q0 + q1) + (q2 + q3)) + ((q4 + q5) + (q6 + q7));
}

__device__ __forceinline__ float proba_np(const float* __restrict__ cbf,
                                          const float* __restrict__ csq,
                                          int c, float4 va, float4 vb, float vsq)
{
#pragma clang fp contract(off)
    float4 ca = ((const float4*)cbf)[2 * c];
    float4 cb = ((const float4*)cbf)[2 * c + 1];
    float p0 = va.x * ca.x, p1 = va.y * ca.y, p2 = va.z * ca.z, p3 = va.w * ca.w;
    float p4 = vb.x * cb.x, p5 = vb.y * cb.y, p6 = vb.z * cb.z, p7 = vb.w * cb.w;
    float l0 = p0 + p4, l1 = p1 + p5, l2 = p2 + p6, l3 = p3 + p7;
    float vc = (l0 + l2) + (l1 + l3);
    float tt = vsq - 2.0f * vc;
    float u  = tt + csq[c];
    return -u;
}

// Exact numpy-order argmax incl. softmax tie path. Byte-identical semantics to
// the round-1/2 kernel that measured absmax == 0.0. Rare (δ-guard) path only.
__device__ __attribute__((noinline))
int exact_search(const float* __restrict__ cbf, const float* __restrict__ csq,
                 float4 va, float4 vb, float vsq)
{
#pragma clang fp contract(off)
    float best = -3.402823466e38f, second = -3.402823466e38f;
    int bi = 0;
    for (int c = 0; c < C; ++c) {
        float pr = proba_np(cbf, csq, c, va, vb, vsq);
        if (pr > best)        { second = best; best = pr; bi = c; }
        else if (pr > second) { second = pr; }
    }
    int idx = bi;

    if (best - second <= 1.0e-6f) {
        float m = best;
        float r0[8] = {0,0,0,0,0,0,0,0};
        float r1[8] = {0,0,0,0,0,0,0,0};
        for (int cg = 0; cg < 16; ++cg) {
            #pragma unroll
            for (int j = 0; j < 8; ++j) {
                float pr = proba_np(cbf, csq, cg * 8 + j, va, vb, vsq);
                r0[j] += expf(pr - m);
            }
        }
        for (int cg = 16; cg < 32; ++cg) {
            #pragma unroll
            for (int j = 0; j < 8; ++j) {
                float pr = proba_np(cbf, csq, cg * 8 + j, va, vb, vsq);
                r1[j] += expf(pr - m);
            }
        }
        float sum = tree8(r0[0],r0[1],r0[2],r0[3],r0[4],r0[5],r0[6],r0[7])
                  + tree8(r1[0],r1[1],r1[2],r1[3],r1[4],r1[5],r1[6],r1[7]);
        float abest = -1.0f;
        int   ai    = 0;
        for (int c = 0; c < C; ++c) {
            float pr = proba_np(cbf, csq, c, va, vb, vsq);
            float e  = expf(pr - m);
            float a  = e / sum;
            if (a > abest) { abest = a; ai = c; }
        }
        idx = ai;
    }
    return idx;
}

// Block = 4 waves x 64 lanes, covers (partition p) x (256 batch rows).
// Wave w scores centroid range [64w, 64w+64) for all 256 rows (4 rows/thread),
// then per-row top-2 partials are merged across waves through LDS.
// Ascending-wave strict-'>' merge over ascending disjoint centroid ranges ==
// sequential first-index-wins scan, so numpy tie semantics are preserved and
// the fast-gap value matches the round-3-validated guard exactly.
__global__ __launch_bounds__(TPB, 6)
void pq_split_kernel(const float* __restrict__ vecs,
                     const float* __restrict__ codebook,
                     float* __restrict__ out)
{
    __shared__ float  cbf [C * SD];          // 8 KB codebook[p]
    __shared__ float  csqn[C];               // ||c||^2 numpy order (exact path)
    __shared__ float  csqh[C];               // -0.5*csq (fast seed)
    __shared__ float2 part_bs[WPB][ROWS][64];  // 8 KB (best, second)
    __shared__ int    part_i [WPB][ROWS][64];  // 4 KB argmax per range

    const int p = blockIdx.x;
    const int t = threadIdx.x;
    const int w = t >> 6;          // wave id 0..3
    const int l = t & 63;          // lane id
    const int rowbase = blockIdx.y * (64 * ROWS);

    // ---- stage codebook[p]: 512 float4, 2 per thread ----
    const float4* src = (const float4*)(codebook + (size_t)p * C * SD);
    ((float4*)cbf)[t]       = src[t];
    ((float4*)cbf)[t + 256] = src[t + 256];
    __syncthreads();

    // ---- csq (numpy order) + fast seed, 1 centroid per thread ----
    {
        const float* cc = cbf + t * SD;
        float q0 = cc[0]*cc[0], q1 = cc[1]*cc[1], q2 = cc[2]*cc[2], q3 = cc[3]*cc[3];
        float q4 = cc[4]*cc[4], q5 = cc[5]*cc[5], q6 = cc[6]*cc[6], q7 = cc[7]*cc[7];
        float s = tree8(q0,q1,q2,q3,q4,q5,q6,q7);
        csqn[t] = s;
        csqh[t] = -0.5f * s;
    }
    __syncthreads();

    // ---- load this thread's ROWS sub-vectors ----
    float4 va[ROWS], vb[ROWS];
    #pragma unroll
    for (int r = 0; r < ROWS; ++r) {
        const float* vptr = vecs + (size_t)(rowbase + 64 * r + l) * D + (size_t)p * SD;
        va[r] = ((const float4*)vptr)[0];
        vb[r] = ((const float4*)vptr)[1];
    }

    // ---- fast scoring over this wave's 64 centroids (branchless top-2) ----
    float best[ROWS], second[ROWS];
    int   bi[ROWS];
    #pragma unroll
    for (int r = 0; r < ROWS; ++r) {
        best[r] = -3.402823466e38f; second[r] = -3.402823466e38f; bi[r] = 0;
    }

    const int c0 = w * CPW;
    #pragma unroll 2
    for (int ci = 0; ci < CPW; ++ci) {
        const int c = c0 + ci;
        float4 ca = ((const float4*)cbf)[2 * c];     // wave-uniform broadcast
        float4 cb = ((const float4*)cbf)[2 * c + 1];
        float  ch = csqh[c];
        #pragma unroll
        for (int r = 0; r < ROWS; ++r) {
            float s = fmaf(va[r].x, ca.x, ch);
            s = fmaf(va[r].y, ca.y, s);
            s = fmaf(va[r].z, ca.z, s);
            s = fmaf(va[r].w, ca.w, s);
            s = fmaf(vb[r].x, cb.x, s);
            s = fmaf(vb[r].y, cb.y, s);
            s = fmaf(vb[r].z, cb.z, s);
            s = fmaf(vb[r].w, cb.w, s);
            bool gt = s > best[r];
            second[r] = fmaxf(second[r], fminf(s, best[r]));
            bi[r]     = gt ? c : bi[r];
            best[r]   = fmaxf(s, best[r]);
        }
    }

    // ---- publish partials ----
    #pragma unroll
    for (int r = 0; r < ROWS; ++r) {
        part_bs[w][r][l] = make_float2(best[r], second[r]);
        part_i [w][r][l] = bi[r];
    }
    __syncthreads();

    // ---- merge: thread t resolves row rowbase + t (its own j == w, lane l) ----
    {
        float Bst = -3.402823466e38f, Snd = -3.402823466e38f;
        int   I   = 0;
        #pragma unroll
        for (int ww = 0; ww < WPB; ++ww) {
            float2 bs = part_bs[ww][w][l];
            int    iw = part_i [ww][w][l];
            bool gt = bs.x > Bst;                 // strict, ascending ww:
            Snd = fmaxf(Snd, fminf(bs.x, Bst));   // first (smaller c) wins ties
            Snd = fmaxf(Snd, bs.y);
            I   = gt ? iw : I;
            Bst = fmaxf(Bst, bs.x);
        }

        const int row = rowbase + t;
        int idx = I;
        if (Bst - Snd <= 2.0e-5f) {               // near-tie: exact numpy path
            const float* vptr = vecs + (size_t)row * D + (size_t)p * SD;
            float4 xa = ((const float4*)vptr)[0];
            float4 xb = ((const float4*)vptr)[1];
            float q0 = xa.x*xa.x, q1 = xa.y*xa.y, q2 = xa.z*xa.z, q3 = xa.w*xa.w;
            float q4 = xb.x*xb.x, q5 = xb.y*xb.y, q6 = xb.z*xb.z, q7 = xb.w*xb.w;
            float vsq = tree8(q0,q1,q2,q3,q4,q5,q6,q7);
            idx = exact_search(cbf, csqn, xa, xb, vsq);
        }

        float4 o0 = ((const float4*)cbf)[2 * idx];
        float4 o1 = ((const float4*)cbf)[2 * idx + 1];
        float4* op = (float4*)(out + (size_t)row * D + (size_t)p * SD);
        op[0] = o0;
        op[1] = o1;
    }
}

extern "C" void kernel_launch(void* const* d_in, const int* in_sizes, int n_in,
                              void* d_out, int out_size, void* d_ws, size_t ws_size,
                              hipStream_t stream)
{
    const float* vecs     = (const float*)d_in[0];  // [B, D] fp32
    const float* codebook = (const float*)d_in[1];  // [P, C, SD] fp32
    float*       out      = (float*)d_out;          // [B, D] fp32

    dim3 grid(P, B / (64 * ROWS));   // (96, 16) -> 1536 blocks x 4 waves
    dim3 block(TPB);
    pq_split_kernel<<<grid, block, 0, stream>>>(vecs, codebook, out);
}